// Round 1
// baseline (12.623 us; speedup 1.0000x reference)
//
#include <hip/hip_runtime.h>
#include <math.h>

// BQNN simulation: per-element 6x3 complex unitary propagation + 20 3x3 permanents.
// One thread per batch element. Thread 0 per block precomputes the batch-independent
// "start" matrix columns 0..2 (S, 6x3 complex) and constant-MZI coefficients into LDS.

__global__ __launch_bounds__(64) void bqnn_kernel(
    const float* __restrict__ x,            // [B,12]
    const float* __restrict__ params,       // [30]  phi=params[0:15], theta=params[15:30]
    const float* __restrict__ output_phase, // [6]
    const float* __restrict__ param_phi,    // [4]
    const float* __restrict__ param_theta,  // [4]
    const float* __restrict__ input_k,      // [12]
    const float* __restrict__ input_b,      // [12]
    float* __restrict__ out,                // [B,20]
    int B)
{
    __shared__ float sSre[6][3], sSim[6][3];
    __shared__ float sC[4][4];   // {ct, st, epr, epi} for const ansatz MZIs j=0..3
    __shared__ float sK[12], sB[12];

    if (threadIdx.x == 0) {
        // Clements mode list for n=6 (15 MZIs)
        const int CM[15][2] = {{0,1},{2,3},{4,5},{1,2},{3,4},
                               {0,1},{2,3},{4,5},{1,2},{3,4},
                               {0,1},{2,3},{4,5},{1,2},{3,4}};
        float Vre[6][3], Vim[6][3];
        #pragma unroll
        for (int r = 0; r < 6; ++r)
            #pragma unroll
            for (int c = 0; c < 3; ++c) { Vre[r][c] = (r == c) ? 1.f : 0.f; Vim[r][c] = 0.f; }
        for (int k = 0; k < 15; ++k) {
            float ct, st, epr, epi;
            __sincosf(params[15 + k], &st, &ct);
            __sincosf(params[k],      &epi, &epr);
            int m = CM[k][0], n = CM[k][1];
            #pragma unroll
            for (int c = 0; c < 3; ++c) {
                float ar = Vre[m][c], ai = Vim[m][c];
                float br = Vre[n][c], bi = Vim[n][c];
                float tr = epr * ar - epi * ai;   // (e^{i phi} * a).re
                float ti = epr * ai + epi * ar;   // (e^{i phi} * a).im
                Vre[m][c] = ct * tr - st * br;
                Vim[m][c] = ct * ti - st * bi;
                Vre[n][c] = st * tr + ct * br;
                Vim[n][c] = st * ti + ct * bi;
            }
        }
        #pragma unroll
        for (int r = 0; r < 6; ++r) {
            float pr, pi;
            __sincosf(output_phase[r], &pi, &pr);
            #pragma unroll
            for (int c = 0; c < 3; ++c) {
                sSre[r][c] = pr * Vre[r][c] - pi * Vim[r][c];
                sSim[r][c] = pr * Vim[r][c] + pi * Vre[r][c];
            }
        }
        #pragma unroll
        for (int j = 0; j < 4; ++j) {
            float ct, st, epr, epi;
            __sincosf(param_theta[j], &st, &ct);
            __sincosf(param_phi[j],   &epi, &epr);
            sC[j][0] = ct; sC[j][1] = st; sC[j][2] = epr; sC[j][3] = epi;
        }
        #pragma unroll
        for (int i = 0; i < 12; ++i) { sK[i] = input_k[i]; sB[i] = input_b[i]; }
    }
    __syncthreads();

    int b = blockIdx.x * blockDim.x + threadIdx.x;
    if (b >= B) return;

    // xs = x * k + b  (row is 48B, float4-aligned)
    const float4* xp = reinterpret_cast<const float4*>(x + (size_t)b * 12);
    float4 a0 = xp[0], a1 = xp[1], a2 = xp[2];
    float xs[12] = {a0.x, a0.y, a0.z, a0.w, a1.x, a1.y, a1.z, a1.w, a2.x, a2.y, a2.z, a2.w};
    #pragma unroll
    for (int i = 0; i < 12; ++i) xs[i] = xs[i] * sK[i] + sB[i];

    // Ansatz MZI coefficients, k=0..9.
    // theta = [xs3,xs4,xs5, pt0,pt1, xs9,xs10,xs11, pt2,pt3]
    // phi   = [xs0,xs1,xs2, pp0,pp1, xs6,xs7, xs8,  pp2,pp3]
    float ct[10], st[10], epr[10], epi[10];
    __sincosf(xs[3],  &st[0], &ct[0]);  __sincosf(xs[0], &epi[0], &epr[0]);
    __sincosf(xs[4],  &st[1], &ct[1]);  __sincosf(xs[1], &epi[1], &epr[1]);
    __sincosf(xs[5],  &st[2], &ct[2]);  __sincosf(xs[2], &epi[2], &epr[2]);
    ct[3] = sC[0][0]; st[3] = sC[0][1]; epr[3] = sC[0][2]; epi[3] = sC[0][3];
    ct[4] = sC[1][0]; st[4] = sC[1][1]; epr[4] = sC[1][2]; epi[4] = sC[1][3];
    __sincosf(xs[9],  &st[5], &ct[5]);  __sincosf(xs[6], &epi[5], &epr[5]);
    __sincosf(xs[10], &st[6], &ct[6]);  __sincosf(xs[7], &epi[6], &epr[6]);
    __sincosf(xs[11], &st[7], &ct[7]);  __sincosf(xs[8], &epi[7], &epr[7]);
    ct[8] = sC[2][0]; st[8] = sC[2][1]; epr[8] = sC[2][2]; epi[8] = sC[2][3];
    ct[9] = sC[3][0]; st[9] = sC[3][1]; epr[9] = sC[3][2]; epi[9] = sC[3][3];

    // V = S (6x3 complex), then apply 10 left-rotations
    float Vre[6][3], Vim[6][3];
    #pragma unroll
    for (int r = 0; r < 6; ++r)
        #pragma unroll
        for (int c = 0; c < 3; ++c) { Vre[r][c] = sSre[r][c]; Vim[r][c] = sSim[r][c]; }

    const int AM[10][2] = {{0,1},{2,3},{4,5},{1,2},{3,4},{0,1},{2,3},{4,5},{1,2},{3,4}};
    #pragma unroll
    for (int k = 0; k < 10; ++k) {
        int m = AM[k][0], n = AM[k][1];
        #pragma unroll
        for (int c = 0; c < 3; ++c) {
            float ar = Vre[m][c], ai = Vim[m][c];
            float br = Vre[n][c], bi = Vim[n][c];
            float tr = epr[k] * ar - epi[k] * ai;
            float ti = epr[k] * ai + epi[k] * ar;
            Vre[m][c] = ct[k] * tr - st[k] * br;
            Vim[m][c] = ct[k] * ti - st[k] * bi;
            Vre[n][c] = st[k] * tr + ct[k] * br;
            Vim[n][c] = st[k] * ti + ct[k] * bi;
        }
    }

    // 2x2 pair permanents for the 10 row-pairs within rows {1..5}
    const int PR[10][2] = {{1,2},{1,3},{1,4},{1,5},{2,3},{2,4},{2,5},{3,4},{3,5},{4,5}};
    float q01r[10], q01i[10], q02r[10], q02i[10], q12r[10], q12i[10];
    #pragma unroll
    for (int p = 0; p < 10; ++p) {
        int i = PR[p][0], j = PR[p][1];
        q01r[p] = (Vre[i][0]*Vre[j][1] - Vim[i][0]*Vim[j][1]) + (Vre[i][1]*Vre[j][0] - Vim[i][1]*Vim[j][0]);
        q01i[p] = (Vre[i][0]*Vim[j][1] + Vim[i][0]*Vre[j][1]) + (Vre[i][1]*Vim[j][0] + Vim[i][1]*Vre[j][0]);
        q02r[p] = (Vre[i][0]*Vre[j][2] - Vim[i][0]*Vim[j][2]) + (Vre[i][2]*Vre[j][0] - Vim[i][2]*Vim[j][0]);
        q02i[p] = (Vre[i][0]*Vim[j][2] + Vim[i][0]*Vre[j][2]) + (Vre[i][2]*Vim[j][0] + Vim[i][2]*Vre[j][0]);
        q12r[p] = (Vre[i][1]*Vre[j][2] - Vim[i][1]*Vim[j][2]) + (Vre[i][2]*Vre[j][1] - Vim[i][2]*Vim[j][1]);
        q12i[p] = (Vre[i][1]*Vim[j][2] + Vim[i][1]*Vre[j][2]) + (Vre[i][2]*Vim[j][1] + Vim[i][2]*Vre[j][1]);
    }

    // 20 triples (a < b < c): perm = Ma0*q12(b,c) + Ma1*q02(b,c) + Ma2*q01(b,c)
    const int TA[20] = {0,0,0,0,0,0,0,0,0,0, 1,1,1,1,1,1, 2,2,2, 3};
    const int TP[20] = {0,1,2,3,4,5,6,7,8,9, 4,5,6,7,8,9, 7,8,9, 9};
    float sq[20];
    float ssum = 0.f;
    #pragma unroll
    for (int t = 0; t < 20; ++t) {
        int a = TA[t], p = TP[t];
        float pr = (Vre[a][0]*q12r[p] - Vim[a][0]*q12i[p])
                 + (Vre[a][1]*q02r[p] - Vim[a][1]*q02i[p])
                 + (Vre[a][2]*q01r[p] - Vim[a][2]*q01i[p]);
        float pi = (Vre[a][0]*q12i[p] + Vim[a][0]*q12r[p])
                 + (Vre[a][1]*q02i[p] + Vim[a][1]*q02r[p])
                 + (Vre[a][2]*q01i[p] + Vim[a][2]*q01r[p]);
        sq[t] = pr * pr + pi * pi;
        ssum += sq[t];
    }
    float inv = 1.f / fmaxf(sqrtf(ssum), 1e-12f);
    float res[20];
    #pragma unroll
    for (int t = 0; t < 20; ++t) res[t] = sqrtf(sq[t]) * inv;

    float4* op = reinterpret_cast<float4*>(out + (size_t)b * 20);
    op[0] = make_float4(res[0],  res[1],  res[2],  res[3]);
    op[1] = make_float4(res[4],  res[5],  res[6],  res[7]);
    op[2] = make_float4(res[8],  res[9],  res[10], res[11]);
    op[3] = make_float4(res[12], res[13], res[14], res[15]);
    op[4] = make_float4(res[16], res[17], res[18], res[19]);
}

extern "C" void kernel_launch(void* const* d_in, const int* in_sizes, int n_in,
                              void* d_out, int out_size, void* d_ws, size_t ws_size,
                              hipStream_t stream) {
    const float* x            = (const float*)d_in[0];
    const float* params       = (const float*)d_in[1];
    const float* output_phase = (const float*)d_in[2];
    const float* param_phi    = (const float*)d_in[3];
    const float* param_theta  = (const float*)d_in[4];
    const float* input_k      = (const float*)d_in[5];
    const float* input_b      = (const float*)d_in[6];
    int B = in_sizes[0] / 12;

    int block = 64;
    int grid = (B + block - 1) / block;
    bqnn_kernel<<<grid, block, 0, stream>>>(x, params, output_phase, param_phi,
                                            param_theta, input_k, input_b,
                                            (float*)d_out, B);
}